// Round 5
// baseline (38.443 us; speedup 1.0000x reference)
//
#include <hip/hip_runtime.h>
#include <math.h>

#define BB 64
#define TT 2048
#define QD 1024
#define AD 256

typedef float f32x4 __attribute__((ext_vector_type(4)));

__device__ __forceinline__ float tanh_fast(float x) {
    // exact algebra: tanh(x) = 1 - 2/(e^{2x}+1); __expf/__fdividef are few-ulp
    float e = __expf(2.0f * x);
    return 1.0f - __fdividef(2.0f, e + 1.0f);
}

// pq[b][a] = sum_q query[b][q] * Wq[a][q]
// one wave per (4 b's x 4 a's) tile: q rows live in registers, Wq read once
// per 4 b's -> L2 traffic ~32MB instead of ~144MB.
__global__ __launch_bounds__(256) void pq_kernel(const float* __restrict__ query,
                                                 const float* __restrict__ Wq,
                                                 float* __restrict__ pq) {
    int wg   = (blockIdx.x * blockDim.x + threadIdx.x) >> 6;  // 0..1023
    int lane = threadIdx.x & 63;
    int b0 = (wg >> 6) * 4;   // 16 b-groups
    int a0 = (wg & 63) * 4;   // 64 a-groups
    float4 qr[4][4];
    #pragma unroll
    for (int i = 0; i < 4; ++i) {
        const float4* qrow = (const float4*)(query + (size_t)(b0 + i) * QD);
        #pragma unroll
        for (int k = 0; k < 4; ++k) qr[i][k] = qrow[lane + k * 64];
    }
    float acc[4][4];
    #pragma unroll
    for (int j = 0; j < 4; ++j) {
        const float4* wrow = (const float4*)(Wq + (size_t)(a0 + j) * QD);
        float4 w4[4];
        #pragma unroll
        for (int k = 0; k < 4; ++k) w4[k] = wrow[lane + k * 64];
        #pragma unroll
        for (int i = 0; i < 4; ++i) {
            float a = 0.f;
            #pragma unroll
            for (int k = 0; k < 4; ++k)
                a += qr[i][k].x * w4[k].x + qr[i][k].y * w4[k].y
                   + qr[i][k].z * w4[k].z + qr[i][k].w * w4[k].w;
            acc[i][j] = a;
        }
    }
    #pragma unroll
    for (int off = 32; off > 0; off >>= 1)
        #pragma unroll
        for (int i = 0; i < 4; ++i)
            #pragma unroll
            for (int j = 0; j < 4; ++j)
                acc[i][j] += __shfl_down(acc[i][j], off, 64);
    if (lane == 0) {
        #pragma unroll
        for (int i = 0; i < 4; ++i) {
            float4 r = make_float4(acc[i][0], acc[i][1], acc[i][2], acc[i][3]);
            ((float4*)(pq + (size_t)(b0 + i) * AD))[a0 >> 2] = r;
        }
    }
}

// For each row (b,t): exp( mask * sum_a tanh(pq[b][a]+esp[b][t][a]) * v[a] )
// (no max subtraction: |energy| <= ||v||_1 ~ 13, exp fits fp32; softmax is
//  shift-invariant so the result is identical).
// One wave per 8 rows: nontemporal float4 stream loads, then an xor-fold
// reduction (10 shuffles for 8 row-sums instead of 48) and an 8-lane epilogue.
__global__ __launch_bounds__(256) void energy_kernel(const float* __restrict__ esp,
                                                     const float* __restrict__ pq,
                                                     const float* __restrict__ v,
                                                     const int* __restrict__ chars,
                                                     float* __restrict__ expout,
                                                     float* __restrict__ partials) {
    __shared__ float red[4];
    int wave = threadIdx.x >> 6;
    int lane = threadIdx.x & 63;
    int wg   = blockIdx.x * 4 + wave;
    size_t r0 = (size_t)wg * 8;          // first of 8 rows (same b: 8 | 2048)
    int b = (int)(r0 >> 11);             // / TT
    float4 p4 = ((const float4*)(pq + (size_t)b * AD))[lane];
    float4 v4 = ((const float4*)v)[lane];

    const f32x4* base = (const f32x4*)(esp + r0 * AD);
    f32x4 e[8];
    #pragma unroll
    for (int j = 0; j < 8; ++j)
        e[j] = __builtin_nontemporal_load(base + j * 64 + lane);

    float s[8];
    #pragma unroll
    for (int j = 0; j < 8; ++j) {
        s[j] = tanh_fast(p4.x + e[j].x) * v4.x
             + tanh_fast(p4.y + e[j].y) * v4.y
             + tanh_fast(p4.z + e[j].z) * v4.z
             + tanh_fast(p4.w + e[j].w) * v4.w;
    }

    // xor-fold: halve the value set per stage. After stage k (bit k of lane),
    // lane keeps rows where lane-bit-k selects the high/low half -> lane bit k
    // carries row-bit (2-k). 10 shuffles total for 8 independent row sums.
    #pragma unroll
    for (int k = 0; k < 3; ++k) {
        int m = 4 >> k;                  // values kept: 4, 2, 1
        int hi = (lane >> k) & 1;
        #pragma unroll
        for (int j = 0; j < m; ++j) {
            float keep = hi ? s[j + m] : s[j];
            float give = hi ? s[j] : s[j + m];
            s[j] = keep + __shfl_xor(give, 1 << k, 64);
        }
    }
    s[0] += __shfl_xor(s[0], 8, 64);
    s[0] += __shfl_xor(s[0], 16, 64);
    s[0] += __shfl_xor(s[0], 32, 64);

    // lane l (l<8) holds the sum for row rev3(l): bit0<->bit2 swapped
    float contrib = 0.f;
    if (lane < 8) {
        int row = ((lane & 1) << 2) | (lane & 2) | ((lane >> 2) & 1);
        int c = chars[r0 + row];
        float ex = c ? __expf(s[0]) : 1.0f;   // masked energy = 0 -> exp = 1
        expout[r0 + row] = ex;
        contrib = ex;
    }
    contrib += __shfl_xor(contrib, 1, 64);
    contrib += __shfl_xor(contrib, 2, 64);
    contrib += __shfl_xor(contrib, 4, 64);
    if (lane == 0) red[wave] = contrib;
    __syncthreads();
    if (threadIdx.x == 0)
        partials[blockIdx.x] = red[0] + red[1] + red[2] + red[3];
}

// one block per b: sum the 64 block-partials, scale the 2048 exp values
__global__ __launch_bounds__(1024) void normalize_kernel(float* __restrict__ io,
                                                         const float* __restrict__ partials) {
    __shared__ float sinv;
    int tid = threadIdx.x;
    int b = blockIdx.x;
    if (tid < 64) {
        float p = partials[b * 64 + tid];
        #pragma unroll
        for (int off = 32; off > 0; off >>= 1)
            p += __shfl_xor(p, off, 64);
        if (tid == 0) sinv = __fdividef(1.0f, p);
    }
    __syncthreads();
    float inv = sinv;
    float2* row = (float2*)(io + (size_t)b * TT);
    float2 vv = row[tid];
    row[tid] = make_float2(vv.x * inv, vv.y * inv);
}

extern "C" void kernel_launch(void* const* d_in, const int* in_sizes, int n_in,
                              void* d_out, int out_size, void* d_ws, size_t ws_size,
                              hipStream_t stream) {
    const float* esp   = (const float*)d_in[0];  // (B,T,AD)
    const float* query = (const float*)d_in[1];  // (B,QD)
    const int*   chars = (const int*)d_in[2];    // (B,T)
    // d_in[3] = t (unused by the reference math)
    const float* Wq    = (const float*)d_in[4];  // (AD,QD)
    const float* v     = (const float*)d_in[5];  // (AD,)
    float* out = (float*)d_out;                  // (B,T)
    float* pq       = (float*)d_ws;                    // B*AD floats
    float* partials = (float*)d_ws + BB * AD;          // 4096 floats

    pq_kernel<<<256, 256, 0, stream>>>(query, Wq, pq);
    energy_kernel<<<(BB * TT) / 32, 256, 0, stream>>>(esp, pq, v, chars, out, partials);
    normalize_kernel<<<BB, 1024, 0, stream>>>(out, partials);
}